// Round 7
// baseline (2099.607 us; speedup 1.0000x reference)
//
#include <hip/hip_runtime.h>
#include <hip/hip_bf16.h>

#define T_TOK 8192
#define HID 2048
#define FFN_ 8192
#define NE 8
#define MAXR 18432   // 16384 + 8*256 padding (segments 256-aligned)

typedef __attribute__((ext_vector_type(8))) short bf16x8;
typedef __attribute__((ext_vector_type(16))) float f32x16;
typedef __attribute__((ext_vector_type(8))) unsigned short u16x8;

__device__ __forceinline__ unsigned short f2bf(float f) {
  unsigned int u = __float_as_uint(f);
  u += 0x7fffu + ((u >> 16) & 1u);   // RNE
  return (unsigned short)(u >> 16);
}
__device__ __forceinline__ float bf2f(unsigned short h) {
  return __uint_as_float(((unsigned int)h) << 16);
}

__device__ __forceinline__ void gload_lds16(const ushort* g, ushort* l) {
  __builtin_amdgcn_global_load_lds(
      (const __attribute__((address_space(1))) unsigned int*)g,
      (__attribute__((address_space(3))) unsigned int*)l, 16, 0, 0);
}

// fast GELU (tanh form, max dev from erf-GELU ~3e-3 << bf16 noise)
__device__ __forceinline__ float gelu_f(float v) {
  float u = v * (0.7978845608f + 0.0356774081f * v * v);
  float a = fabsf(u);
  float ex = __expf(-2.f * a);
  float r = 1.f / (1.f + ex);
  float th = (1.f - ex) * r;
  th = (u >= 0.f) ? th : -th;
  return 0.5f * v * (1.f + th);
}

// ---------------- router: one wave per token ----------------
__global__ __launch_bounds__(256) void router_kernel(
    const float* __restrict__ x, const float* __restrict__ gw,
    int* __restrict__ topk_idx, float* __restrict__ topk_w, int* __restrict__ counts)
{
  int lane = threadIdx.x & 63;
  int w = threadIdx.x >> 6;
  int t = blockIdx.x * 4 + w;
  const float* xr = x + (size_t)t * HID;
  float acc[NE];
#pragma unroll
  for (int e = 0; e < NE; ++e) acc[e] = 0.f;
  for (int h = lane; h < HID; h += 64) {
    float xv = xr[h];
#pragma unroll
    for (int e = 0; e < NE; ++e) acc[e] = fmaf(xv, gw[e * HID + h], acc[e]);
  }
#pragma unroll
  for (int e = 0; e < NE; ++e) {
#pragma unroll
    for (int s = 32; s > 0; s >>= 1) acc[e] += __shfl_xor(acc[e], s);
  }
  if (lane == 0) {
    int i0 = 0; float v0 = acc[0];
#pragma unroll
    for (int e = 1; e < NE; ++e) { if (acc[e] > v0) { v0 = acc[e]; i0 = e; } }
    int i1 = -1; float v1 = -3.4e38f;
#pragma unroll
    for (int e = 0; e < NE; ++e) { if (e != i0 && acc[e] > v1) { v1 = acc[e]; i1 = e; } }
    float r = __expf(v1 - v0);
    float w0 = 1.f / (1.f + r);
    float w1 = r * w0;
    topk_idx[2 * t] = i0; topk_idx[2 * t + 1] = i1;
    topk_w[2 * t] = w0;   topk_w[2 * t + 1] = w1;
    atomicAdd(&counts[i0], 1);
    atomicAdd(&counts[i1], 1);
  }
}

__global__ void offsets_kernel(const int* __restrict__ counts, int* __restrict__ offs) {
  if (threadIdx.x == 0 && blockIdx.x == 0) {
    int o = 0;
#pragma unroll
    for (int e = 0; e < NE; ++e) { offs[e] = o; o += (counts[e] + 255) & ~255; }
    offs[NE] = o;
  }
}

__global__ __launch_bounds__(256) void scatter_kernel(
    const int* __restrict__ topk_idx, const float* __restrict__ topk_w,
    const int* __restrict__ offs, int* __restrict__ cursors,
    int* __restrict__ slot_token, float* __restrict__ slot_w, int* __restrict__ token_slot)
{
  int t = blockIdx.x * blockDim.x + threadIdx.x;
  if (t >= T_TOK) return;
#pragma unroll
  for (int k = 0; k < 2; ++k) {
    int e = topk_idx[2 * t + k];
    int pos = atomicAdd(&cursors[e], 1);
    int slot = offs[e] + pos;
    slot_token[slot] = t;
    slot_w[slot] = topk_w[2 * t + k];
    token_slot[2 * t + k] = slot;
  }
}

// gather token rows into bf16, one block per slot row
__global__ __launch_bounds__(256) void gather_kernel(
    const float* __restrict__ x, const int* __restrict__ slot_token, ushort* __restrict__ Xg)
{
  int row = blockIdx.x;
  int tok = slot_token[row];
  ushort* dst = Xg + (size_t)row * HID + threadIdx.x * 8;
  if (tok < 0) {
    u16x8 z = {0, 0, 0, 0, 0, 0, 0, 0};
    *(u16x8*)dst = z;
  } else {
    const float* s = x + (size_t)tok * HID + threadIdx.x * 8;
    float4 a = *(const float4*)s;
    float4 b = *(const float4*)(s + 4);
    u16x8 v;
    v[0] = f2bf(a.x); v[1] = f2bf(a.y); v[2] = f2bf(a.z); v[3] = f2bf(a.w);
    v[4] = f2bf(b.x); v[5] = f2bf(b.y); v[6] = f2bf(b.z); v[7] = f2bf(b.w);
    *(u16x8*)dst = v;
  }
}

// fp32 [E][R][C] -> bf16 [E][C][R]
__global__ __launch_bounds__(256) void transpose_convert_kernel(
    const float* __restrict__ src, ushort* __restrict__ dst, int R, int C)
{
  __shared__ float tile[64][65];
  int e = blockIdx.z;
  const float* s = src + (size_t)e * R * C;
  ushort* d = dst + (size_t)e * R * C;
  int r0 = blockIdx.y << 6, c0 = blockIdx.x << 6;
  int t = threadIdx.x;
#pragma unroll
  for (int i = 0; i < 4; ++i) {
    int idx = i * 256 + t;
    int row = idx >> 4;
    int c4 = (idx & 15) << 2;
    float4 v = *(const float4*)&s[(size_t)(r0 + row) * C + (c0 + c4)];
    tile[row][c4 + 0] = v.x; tile[row][c4 + 1] = v.y;
    tile[row][c4 + 2] = v.z; tile[row][c4 + 3] = v.w;
  }
  __syncthreads();
#pragma unroll
  for (int i = 0; i < 8; ++i) {
    int idx = (i * 256 + t) * 2;
    int orow = idx >> 6;
    int ocol = idx & 63;
    ushort2 p;
    p.x = f2bf(tile[ocol][orow]);
    p.y = f2bf(tile[ocol + 1][orow]);
    *(ushort2*)&d[(size_t)(c0 + orow) * R + (r0 + ocol)] = p;
  }
}

// ============ GEMM 256x256, BK=64, 8 waves, 8-phase / 4-barrier, 32x32x16 MFMA ============
// C[row][col] = A[row][:] . Bt[col][:]  (both K-contiguous)
// LDS per buffer (ushort): [A_first 8192][A_second 8192][B_first 8192][B_second 8192]
// Per 128x64 region: 16B chunk j of phys row p stored at physical chunk j^(p&7).
// global_load_lds writes LINEAR; source global addr pre-swizzled (rule 21).
// Staging maps, vmcnt(6) ledger, 4-barrier schedule: identical to r6 (proven).
//
// MFMA core: v_mfma_f32_32x32x16_bf16. Per wave: output 128x64 as 4 m-blocks
// (32 rows) x 2 n-blocks (32 cols); per phase (MQ,NQ): 2 mb x 4 kslices = 8 MFMA.
// A frag: lane l holds row l&31, k = ks*16 + (l>>5)*8 + j  (analog of validated 16x16 map)
// B frag: lane l holds col l&31, same k
// C/D:    col = lane&31, row = (reg&3) + 8*(reg>>2) + 4*(lane>>5)   [m74/m101 verified]
// LDS read count per phase unchanged vs r6 (8 A + 4 B b128); bank-spread re-checked
// conflict-free (chunk = (2ks+khalf)^(l&7), 32 lanes -> 4x over 8 chunk slots).

#define VMW6() do { asm volatile("s_waitcnt vmcnt(6)" ::: "memory"); } while (0)
#define VMW0() do { asm volatile("s_waitcnt vmcnt(0)" ::: "memory"); } while (0)
#define SCB()  __builtin_amdgcn_sched_barrier(0)
#define BAR()  __builtin_amdgcn_s_barrier()

#define STG_A(BUF, HALF, T) do {                                            \
    ushort* _d = lds + (BUF) * 32768 + (HALF) * 8192 + tid * 8;             \
    gload_lds16(sA0 + (size_t)(HALF) * 64 * K + (size_t)(T) * 64, _d);      \
    gload_lds16(sA1 + (size_t)(HALF) * 64 * K + (size_t)(T) * 64, _d + 4096); \
  } while (0)
#define STG_B(BUF, HALF, T) do {                                            \
    ushort* _d = lds + (BUF) * 32768 + 16384 + (HALF) * 8192 + tid * 8;     \
    gload_lds16(sB0 + (size_t)(HALF) * 32 * K + (size_t)(T) * 64, _d);      \
    gload_lds16(sB1 + (size_t)(HALF) * 32 * K + (size_t)(T) * 64, _d + 4096); \
  } while (0)

#define LDA32(BUF, MQ) do {                                                 \
    _Pragma("unroll") for (int mb = 0; mb < 2; ++mb) {                      \
      const ushort* _p = lds + (BUF) * 32768 + (MQ) * 8192 + aoff32 + mb * 2048; \
      af[mb][0] = *(const bf16x8*)(_p + ck0);                               \
      af[mb][1] = *(const bf16x8*)(_p + ck1);                               \
      af[mb][2] = *(const bf16x8*)(_p + ck2);                               \
      af[mb][3] = *(const bf16x8*)(_p + ck3);                               \
    } } while (0)
#define LDB32(BUF, NQ) do {                                                 \
      const ushort* _p = lds + (BUF) * 32768 + 16384 + (NQ) * 8192 + boff32; \
      bfr[NQ][0] = *(const bf16x8*)(_p + ck0);                              \
      bfr[NQ][1] = *(const bf16x8*)(_p + ck1);                              \
      bfr[NQ][2] = *(const bf16x8*)(_p + ck2);                              \
      bfr[NQ][3] = *(const bf16x8*)(_p + ck3);                              \
  } while (0)

// per-phase MFMA cluster: wait own ds_reads, no barrier; ks-outer/mb-inner for
// 2 independent acc chains interleaved.
#define MM32(MQ, NQ) do {                                                   \
    asm volatile("s_waitcnt lgkmcnt(0)" ::: "memory");                      \
    __builtin_amdgcn_sched_barrier(0);                                      \
    __builtin_amdgcn_s_setprio(1);                                          \
    _Pragma("unroll") for (int ks = 0; ks < 4; ++ks)                        \
    _Pragma("unroll") for (int mb = 0; mb < 2; ++mb) {                      \
      acc[(MQ)*2+mb][(NQ)] = __builtin_amdgcn_mfma_f32_32x32x16_bf16(       \
          af[mb][ks], bfr[(NQ)][ks], acc[(MQ)*2+mb][(NQ)], 0, 0, 0);        \
    }                                                                       \
    __builtin_amdgcn_s_setprio(0);                                          \
    __builtin_amdgcn_sched_barrier(0);                                      \
  } while (0)

template <int EPI>
__global__ __launch_bounds__(512, 2) void gemm256_kernel(
    const ushort* __restrict__ A, const ushort* __restrict__ Bt,
    const float* __restrict__ bias, ushort* __restrict__ Cout,
    const float* __restrict__ slot_w, const int* __restrict__ offs,
    int K, int N, int gy)
{
  __shared__ ushort lds[65536];   // 128 KiB

  const int tid = threadIdx.x;
  // XCD-chunked swizzle + column-major decode within chunk (r5/r6, proven):
  // consecutive same-XCD blocks share a B (weight) panel and march down rows.
  int nwg = gridDim.x;
  int wg = blockIdx.x;
  int cpx = nwg >> 3;
  wg = (wg & 7) * cpx + (wg >> 3);
  int cb = wg / gy;
  int rb = wg - cb * gy;

  int total = offs[NE];
  int row0 = rb * 256;
  if (row0 >= total) return;
  int e = 0;
#pragma unroll
  for (int i = 1; i < NE; ++i) e += (row0 >= offs[i]) ? 1 : 0;

  const ushort* Ag = A + (size_t)row0 * K;
  const ushort* Bg = Bt + ((size_t)e * N + (size_t)cb * 256) * K;

  // staging source (pre-swizzled); LDS dest linear  -- unchanged from r6
  const int pr0 = tid >> 3;
  const int pr1 = 64 + pr0;
  const int j0 = (tid & 7) ^ (pr0 & 7);
  const int j1 = (tid & 7) ^ (pr1 & 7);
  const int rA0 = pr0;                              // A map: (p>>6)*128 + (p&63)
  const int rA1 = 128 + pr0;
  const int rB0 = ((pr0 >> 5) << 6) + (pr0 & 31);   // B map: (p>>5)*64 + (p&31)
  const int rB1 = ((pr1 >> 5) << 6) + (pr1 & 31);
  const ushort* sA0 = Ag + (size_t)rA0 * K + j0 * 8;
  const ushort* sA1 = Ag + (size_t)rA1 * K + j1 * 8;
  const ushort* sB0 = Bg + (size_t)rB0 * K + j0 * 8;
  const ushort* sB1 = Bg + (size_t)rB1 * K + j1 * 8;

  // fragment read addressing (32x32x16)
  const int lane = tid & 63;
  const int wid = tid >> 6;
  const int wr = wid >> 2, wc = wid & 3;    // wave grid 2(M) x 4(N)
  const int l31 = lane & 31, khalf = lane >> 5, x7 = lane & 7;
  const int ck0 = ((0 * 2 + khalf) ^ x7) * 8;   // swizzled 16B chunk, ks=0
  const int ck1 = ((1 * 2 + khalf) ^ x7) * 8;   // ks=1
  const int ck2 = ((2 * 2 + khalf) ^ x7) * 8;   // ks=2
  const int ck3 = ((3 * 2 + khalf) ^ x7) * 8;   // ks=3
  const int aoff32 = (wr * 64 + l31) * 64;  // phys-row offset within A region
  const int boff32 = (wc * 32 + l31) * 64;  // within B region

  f32x16 acc[4][2] = {};
  bf16x8 af[2][4], bfr[2][4];

  const int NT = K >> 6;
  const int NITER = NT >> 1;

  // prologue: tile0 full + tile1 {A_first,B_first,B_second}; wait tile0 landed
  STG_A(0, 0, 0); STG_A(0, 1, 0); STG_B(0, 0, 0); STG_B(0, 1, 0);
  STG_A(1, 0, 1); STG_B(1, 0, 1); STG_B(1, 1, 1);
  VMW6();
  BAR(); SCB();

  for (int it = 0; it < NITER; ++it) {
    const int tb = 2 * it + 1;
    const int tn0 = 2 * it + 2;
    const int tn1 = 2 * it + 3;
    const bool more0 = tn0 < NT;
    const bool more1 = tn1 < NT;
    const bool last = (it + 1 == NITER);

    // ===== group 1: ph1, ph2 =====
    STG_A(1, 1, tb);             // buf1.A2 <- tile tb (read prev-ph7; B4 between)
    LDA32(0, 0); LDB32(0, 0);
    MM32(0, 0);
    LDB32(0, 1);
    MM32(0, 1);
    BAR(); SCB();                // B1

    // ===== group 2: ph3, ph4 =====
    if (more0) { STG_A(0, 0, tn0); STG_B(0, 0, tn0); }   // read@ph1 (B1 between)
    LDA32(0, 1);
    MM32(1, 0);
    if (more0) STG_B(0, 1, tn0);                          // read@ph2 (B1)
    MM32(1, 1);
    if (last) { VMW0(); } else { VMW6(); }   // RAW gate for buf1 reads
    BAR(); SCB();                // B2

    // ===== group 3: ph5, ph6 =====
    if (more0) STG_A(0, 1, tn0);                          // read@ph3 (B2)
    LDA32(1, 0); LDB32(1, 0);
    MM32(0, 0);
    LDB32(1, 1);
    MM32(0, 1);
    BAR(); SCB();                // B3

    // ===== group 4: ph7, ph8 =====
    if (more1) { STG_A(1, 0, tn1); STG_B(1, 0, tn1); }    // read@ph5 (B3)
    LDA32(1, 1);
    MM32(1, 0);
    if (more1) STG_B(1, 1, tn1);                          // read@ph6 (B3)
    MM32(1, 1);
    if (more1) VMW6();           // RAW gate for next-iter buf0 reads
    BAR(); SCB();                // B4
  }

  // epilogue (32x32 C/D layout): col = lane&31 (B-dim), per acc-reg r:
  // row = (r&3) + 8*(r>>2) + 4*khalf within the 32-row m-block.
  const int colb = cb * 256 + wc * 64;
  const int rowb = row0 + wr * 128;
#pragma unroll
  for (int nb = 0; nb < 2; ++nb) {
    const int gc = colb + nb * 32 + l31;
    const float bv = bias[(size_t)e * N + gc];
#pragma unroll
    for (int am = 0; am < 4; ++am) {
      const int rbase = rowb + am * 32 + 4 * khalf;
#pragma unroll
      for (int r = 0; r < 16; ++r) {
        const int grow = rbase + (r & 3) + 8 * (r >> 2);
        float v = acc[am][nb][r] + bv;
        if (EPI == 0) v = gelu_f(v);
        else          v *= slot_w[grow];
        Cout[(size_t)grow * N + gc] = f2bf(v);
      }
    }
  }
}

// out = x + Y[slot0] + Y[slot1]
__global__ __launch_bounds__(256) void combine_kernel(
    const float* __restrict__ x, const ushort* __restrict__ Yp,
    const int* __restrict__ token_slot, float* __restrict__ out)
{
  int t = blockIdx.x;
  int s0 = token_slot[2 * t], s1 = token_slot[2 * t + 1];
  int c = threadIdx.x * 8;
  const float* xr = x + (size_t)t * HID + c;
  u16x8 y0 = *(const u16x8*)&Yp[(size_t)s0 * HID + c];
  u16x8 y1 = *(const u16x8*)&Yp[(size_t)s1 * HID + c];
  float4 xa = *(const float4*)xr;
  float4 xb = *(const float4*)(xr + 4);
  float4 oa, ob;
  oa.x = xa.x + bf2f(y0[0]) + bf2f(y1[0]);
  oa.y = xa.y + bf2f(y0[1]) + bf2f(y1[1]);
  oa.z = xa.z + bf2f(y0[2]) + bf2f(y1[2]);
  oa.w = xa.w + bf2f(y0[3]) + bf2f(y1[3]);
  ob.x = xb.x + bf2f(y0[4]) + bf2f(y1[4]);
  ob.y = xb.y + bf2f(y0[5]) + bf2f(y1[5]);
  ob.z = xb.z + bf2f(y0[6]) + bf2f(y1[6]);
  ob.w = xb.w + bf2f(y0[7]) + bf2f(y1[7]);
  float* orow = out + (size_t)t * HID + c;
  *(float4*)orow = oa;
  *(float4*)(orow + 4) = ob;
}

extern "C" void kernel_launch(void* const* d_in, const int* in_sizes, int n_in,
                              void* d_out, int out_size, void* d_ws, size_t ws_size,
                              hipStream_t stream)
{
  const float* x  = (const float*)d_in[0];
  const float* gw = (const float*)d_in[1];
  const float* w1 = (const float*)d_in[2];
  const float* b1 = (const float*)d_in[3];
  const float* w2 = (const float*)d_in[4];
  const float* b2 = (const float*)d_in[5];
  float* out = (float*)d_out;

  char* ws = (char*)d_ws;
  // wT holds w1t during gemm1, then w2t for gemm2.
  ushort* wT  = (ushort*)(ws + 0);            // [E][out][K] bf16: 268,435,456
  ushort* Hb  = (ushort*)(ws + 268435456);    // [MAXR][FFN] bf16: 301,989,888
  ushort* Xg  = (ushort*)(ws + 570425344);    // [MAXR][HID] bf16: 75,497,472
  ushort* Yp  = Xg;                           // Ypair overlays Xg
  char* sm = ws + 645922816;
  int*   slot_token = (int*)(sm);
  float* slot_w     = (float*)(sm + 73728);
  int*   token_slot = (int*)(sm + 147456);
  int*   topk_idx   = (int*)(sm + 212992);
  float* topk_w     = (float*)(sm + 278528);
  int*   counts     = (int*)(sm + 344064);
  int*   cursors    = (int*)(sm + 344096);
  int*   offs       = (int*)(sm + 344128);

  hipMemsetAsync(counts, 0, 64, stream);
  hipMemsetAsync(slot_token, 0xFF, MAXR * 4, stream);

  router_kernel<<<dim3(T_TOK / 4), dim3(256), 0, stream>>>(x, gw, topk_idx, topk_w, counts);
  offsets_kernel<<<dim3(1), dim3(64), 0, stream>>>(counts, offs);
  scatter_kernel<<<dim3(T_TOK / 256), dim3(256), 0, stream>>>(
      topk_idx, topk_w, offs, cursors, slot_token, slot_w, token_slot);
  gather_kernel<<<dim3(MAXR), dim3(256), 0, stream>>>(x, slot_token, Xg);

  // w1 fp32 [H][F] -> bf16 [F][H] per expert
  transpose_convert_kernel<<<dim3(FFN_ / 64, HID / 64, NE), dim3(256), 0, stream>>>(
      w1, wT, HID, FFN_);
  gemm256_kernel<0><<<dim3((FFN_ / 256) * (MAXR / 256)), dim3(512), 0, stream>>>(
      Xg, wT, b1, Hb, nullptr, offs, HID, FFN_, MAXR / 256);

  // w2 fp32 [F][H] -> bf16 [H][F] per expert (reuses wT)
  transpose_convert_kernel<<<dim3(HID / 64, FFN_ / 64, NE), dim3(256), 0, stream>>>(
      w2, wT, FFN_, HID);
  gemm256_kernel<1><<<dim3((HID / 256) * (MAXR / 256)), dim3(512), 0, stream>>>(
      Hb, wT, b2, Yp, slot_w, offs, FFN_, HID, MAXR / 256);

  combine_kernel<<<dim3(T_TOK), dim3(256), 0, stream>>>(x, Yp, token_slot, out);
}

// Round 8
// 1851.057 us; speedup vs baseline: 1.1343x; 1.1343x over previous
//
#include <hip/hip_runtime.h>
#include <hip/hip_bf16.h>

#define T_TOK 8192
#define HID 2048
#define FFN_ 8192
#define NE 8
#define MAXR 18432   // 16384 + 8*256 padding (segments 256-aligned)

typedef __attribute__((ext_vector_type(8))) short bf16x8;
typedef __attribute__((ext_vector_type(4))) float f32x4;
typedef __attribute__((ext_vector_type(8))) unsigned short u16x8;

__device__ __forceinline__ unsigned short f2bf(float f) {
  unsigned int u = __float_as_uint(f);
  u += 0x7fffu + ((u >> 16) & 1u);   // RNE
  return (unsigned short)(u >> 16);
}
__device__ __forceinline__ float bf2f(unsigned short h) {
  return __uint_as_float(((unsigned int)h) << 16);
}

__device__ __forceinline__ void gload_lds16(const ushort* g, ushort* l) {
  __builtin_amdgcn_global_load_lds(
      (const __attribute__((address_space(1))) unsigned int*)g,
      (__attribute__((address_space(3))) unsigned int*)l, 16, 0, 0);
}

// fast GELU (tanh form, max dev from erf-GELU ~3e-3 << bf16 noise)
__device__ __forceinline__ float gelu_f(float v) {
  float u = v * (0.7978845608f + 0.0356774081f * v * v);
  float a = fabsf(u);
  float ex = __expf(-2.f * a);
  float r = 1.f / (1.f + ex);
  float th = (1.f - ex) * r;
  th = (u >= 0.f) ? th : -th;
  return 0.5f * v * (1.f + th);
}

// ---------------- router: one wave per token ----------------
__global__ __launch_bounds__(256) void router_kernel(
    const float* __restrict__ x, const float* __restrict__ gw,
    int* __restrict__ topk_idx, float* __restrict__ topk_w, int* __restrict__ counts)
{
  int lane = threadIdx.x & 63;
  int w = threadIdx.x >> 6;
  int t = blockIdx.x * 4 + w;
  const float* xr = x + (size_t)t * HID;
  float acc[NE];
#pragma unroll
  for (int e = 0; e < NE; ++e) acc[e] = 0.f;
  for (int h = lane; h < HID; h += 64) {
    float xv = xr[h];
#pragma unroll
    for (int e = 0; e < NE; ++e) acc[e] = fmaf(xv, gw[e * HID + h], acc[e]);
  }
#pragma unroll
  for (int e = 0; e < NE; ++e) {
#pragma unroll
    for (int s = 32; s > 0; s >>= 1) acc[e] += __shfl_xor(acc[e], s);
  }
  if (lane == 0) {
    int i0 = 0; float v0 = acc[0];
#pragma unroll
    for (int e = 1; e < NE; ++e) { if (acc[e] > v0) { v0 = acc[e]; i0 = e; } }
    int i1 = -1; float v1 = -3.4e38f;
#pragma unroll
    for (int e = 0; e < NE; ++e) { if (e != i0 && acc[e] > v1) { v1 = acc[e]; i1 = e; } }
    float r = __expf(v1 - v0);
    float w0 = 1.f / (1.f + r);
    float w1 = r * w0;
    topk_idx[2 * t] = i0; topk_idx[2 * t + 1] = i1;
    topk_w[2 * t] = w0;   topk_w[2 * t + 1] = w1;
    atomicAdd(&counts[i0], 1);
    atomicAdd(&counts[i1], 1);
  }
}

__global__ void offsets_kernel(const int* __restrict__ counts, int* __restrict__ offs) {
  if (threadIdx.x == 0 && blockIdx.x == 0) {
    int o = 0;
#pragma unroll
    for (int e = 0; e < NE; ++e) { offs[e] = o; o += (counts[e] + 255) & ~255; }
    offs[NE] = o;
  }
}

__global__ __launch_bounds__(256) void scatter_kernel(
    const int* __restrict__ topk_idx, const float* __restrict__ topk_w,
    const int* __restrict__ offs, int* __restrict__ cursors,
    int* __restrict__ slot_token, float* __restrict__ slot_w, int* __restrict__ token_slot)
{
  int t = blockIdx.x * blockDim.x + threadIdx.x;
  if (t >= T_TOK) return;
#pragma unroll
  for (int k = 0; k < 2; ++k) {
    int e = topk_idx[2 * t + k];
    int pos = atomicAdd(&cursors[e], 1);
    int slot = offs[e] + pos;
    slot_token[slot] = t;
    slot_w[slot] = topk_w[2 * t + k];
    token_slot[2 * t + k] = slot;
  }
}

// gather token rows into bf16, one block per slot row
__global__ __launch_bounds__(256) void gather_kernel(
    const float* __restrict__ x, const int* __restrict__ slot_token, ushort* __restrict__ Xg)
{
  int row = blockIdx.x;
  int tok = slot_token[row];
  ushort* dst = Xg + (size_t)row * HID + threadIdx.x * 8;
  if (tok < 0) {
    u16x8 z = {0, 0, 0, 0, 0, 0, 0, 0};
    *(u16x8*)dst = z;
  } else {
    const float* s = x + (size_t)tok * HID + threadIdx.x * 8;
    float4 a = *(const float4*)s;
    float4 b = *(const float4*)(s + 4);
    u16x8 v;
    v[0] = f2bf(a.x); v[1] = f2bf(a.y); v[2] = f2bf(a.z); v[3] = f2bf(a.w);
    v[4] = f2bf(b.x); v[5] = f2bf(b.y); v[6] = f2bf(b.z); v[7] = f2bf(b.w);
    *(u16x8*)dst = v;
  }
}

// fp32 [E][R][C] -> bf16 [E][C][R]
__global__ __launch_bounds__(256) void transpose_convert_kernel(
    const float* __restrict__ src, ushort* __restrict__ dst, int R, int C)
{
  __shared__ float tile[64][65];
  int e = blockIdx.z;
  const float* s = src + (size_t)e * R * C;
  ushort* d = dst + (size_t)e * R * C;
  int r0 = blockIdx.y << 6, c0 = blockIdx.x << 6;
  int t = threadIdx.x;
#pragma unroll
  for (int i = 0; i < 4; ++i) {
    int idx = i * 256 + t;
    int row = idx >> 4;
    int c4 = (idx & 15) << 2;
    float4 v = *(const float4*)&s[(size_t)(r0 + row) * C + (c0 + c4)];
    tile[row][c4 + 0] = v.x; tile[row][c4 + 1] = v.y;
    tile[row][c4 + 2] = v.z; tile[row][c4 + 3] = v.w;
  }
  __syncthreads();
#pragma unroll
  for (int i = 0; i < 8; ++i) {
    int idx = (i * 256 + t) * 2;
    int orow = idx >> 6;
    int ocol = idx & 63;
    ushort2 p;
    p.x = f2bf(tile[ocol][orow]);
    p.y = f2bf(tile[ocol + 1][orow]);
    *(ushort2*)&d[(size_t)(c0 + orow) * R + (r0 + ocol)] = p;
  }
}

// ============ GEMM 256x256, BK=64, 8 waves, 8-phase / 4-barrier, compiler-scheduled ======
// C[row][col] = A[row][:] . Bt[col][:]  (both K-contiguous)
// LDS per buffer (ushort): [A_first 8192][A_second 8192][B_first 8192][B_second 8192]
// Per 128x64 region: 16B chunk j of phys row p stored at physical chunk j^(p&7).
// global_load_lds writes LINEAR; source global addr pre-swizzled (rule 21).
// Staging maps, vmcnt(6) ledger, 4-barrier schedule: identical to r6 (proven).
//
// r8 change vs r6: MM drops the asm lgkmcnt(0)+sched_barrier. ds_reads are plain
// C++ loads, so the compiler tracks af/bf register deps and emits minimal COUNTED
// lgkmcnt waits (m97-verified behavior); the asm full-drain per phase was forcing
// 8x ~250cyc LDS-latency exposures per iter. Group bodies list all reads before
// the two MFMA clusters; group boundaries stay pinned by BAR()+sched_barrier(0),
// so the WAR/RAW ledger is unchanged from r6.

#define VMW6() do { asm volatile("s_waitcnt vmcnt(6)" ::: "memory"); } while (0)
#define VMW0() do { asm volatile("s_waitcnt vmcnt(0)" ::: "memory"); } while (0)
#define SCB()  __builtin_amdgcn_sched_barrier(0)
#define BAR()  __builtin_amdgcn_s_barrier()

#define STG_A(BUF, HALF, T) do {                                            \
    ushort* _d = lds + (BUF) * 32768 + (HALF) * 8192 + tid * 8;             \
    gload_lds16(sA0 + (size_t)(HALF) * 64 * K + (size_t)(T) * 64, _d);      \
    gload_lds16(sA1 + (size_t)(HALF) * 64 * K + (size_t)(T) * 64, _d + 4096); \
  } while (0)
#define STG_B(BUF, HALF, T) do {                                            \
    ushort* _d = lds + (BUF) * 32768 + 16384 + (HALF) * 8192 + tid * 8;     \
    gload_lds16(sB0 + (size_t)(HALF) * 32 * K + (size_t)(T) * 64, _d);      \
    gload_lds16(sB1 + (size_t)(HALF) * 32 * K + (size_t)(T) * 64, _d + 4096); \
  } while (0)

#define LDA(BUF, MQ) do {                                                   \
    _Pragma("unroll") for (int mm = 0; mm < 4; ++mm) {                      \
      const ushort* _p = lds + (BUF) * 32768 + (MQ) * 8192 + aoff + mm * 1024; \
      af[mm][0] = *(const bf16x8*)(_p + ck0);                               \
      af[mm][1] = *(const bf16x8*)(_p + ck1);                               \
    } } while (0)
#define LDB(BUF, NQ) do {                                                   \
    _Pragma("unroll") for (int nn = 0; nn < 2; ++nn) {                      \
      const ushort* _p = lds + (BUF) * 32768 + 16384 + (NQ) * 8192 + boff + nn * 1024; \
      bf[NQ][nn][0] = *(const bf16x8*)(_p + ck0);                           \
      bf[NQ][nn][1] = *(const bf16x8*)(_p + ck1);                           \
    } } while (0)

// MFMA cluster: setprio only; compiler inserts minimal counted lgkmcnt waits
// for the af/bf register deps (plain-load ds_reads -> precise dep tracking).
#define MM(MQ, NQ) do {                                                     \
    __builtin_amdgcn_s_setprio(1);                                          \
    _Pragma("unroll") for (int mm = 0; mm < 4; ++mm)                        \
    _Pragma("unroll") for (int nn = 0; nn < 2; ++nn) {                      \
      acc[(MQ)*4+mm][(NQ)*2+nn] = __builtin_amdgcn_mfma_f32_16x16x32_bf16(  \
          af[mm][0], bf[NQ][nn][0], acc[(MQ)*4+mm][(NQ)*2+nn], 0, 0, 0);    \
      acc[(MQ)*4+mm][(NQ)*2+nn] = __builtin_amdgcn_mfma_f32_16x16x32_bf16(  \
          af[mm][1], bf[NQ][nn][1], acc[(MQ)*4+mm][(NQ)*2+nn], 0, 0, 0);    \
    }                                                                       \
    __builtin_amdgcn_s_setprio(0);                                          \
  } while (0)

template <int EPI>
__global__ __launch_bounds__(512, 2) void gemm256_kernel(
    const ushort* __restrict__ A, const ushort* __restrict__ Bt,
    const float* __restrict__ bias, ushort* __restrict__ Cout,
    const float* __restrict__ slot_w, const int* __restrict__ offs,
    int K, int N, int gy)
{
  __shared__ ushort lds[65536];   // 128 KiB

  const int tid = threadIdx.x;
  // XCD-chunked swizzle + column-major decode within chunk (r5/r6, proven):
  // consecutive same-XCD blocks share a B (weight) panel and march down rows.
  int nwg = gridDim.x;
  int wg = blockIdx.x;
  int cpx = nwg >> 3;
  wg = (wg & 7) * cpx + (wg >> 3);
  int cb = wg / gy;
  int rb = wg - cb * gy;

  int total = offs[NE];
  int row0 = rb * 256;
  if (row0 >= total) return;
  int e = 0;
#pragma unroll
  for (int i = 1; i < NE; ++i) e += (row0 >= offs[i]) ? 1 : 0;

  const ushort* Ag = A + (size_t)row0 * K;
  const ushort* Bg = Bt + ((size_t)e * N + (size_t)cb * 256) * K;

  // staging source (pre-swizzled); LDS dest linear
  const int pr0 = tid >> 3;
  const int pr1 = 64 + pr0;
  const int j0 = (tid & 7) ^ (pr0 & 7);
  const int j1 = (tid & 7) ^ (pr1 & 7);
  const int rA0 = pr0;                              // A map: (p>>6)*128 + (p&63)
  const int rA1 = 128 + pr0;
  const int rB0 = ((pr0 >> 5) << 6) + (pr0 & 31);   // B map: (p>>5)*64 + (p&31)
  const int rB1 = ((pr1 >> 5) << 6) + (pr1 & 31);
  const ushort* sA0 = Ag + (size_t)rA0 * K + j0 * 8;
  const ushort* sA1 = Ag + (size_t)rA1 * K + j1 * 8;
  const ushort* sB0 = Bg + (size_t)rB0 * K + j0 * 8;
  const ushort* sB1 = Bg + (size_t)rB1 * K + j1 * 8;

  // fragment read addressing
  const int lane = tid & 63;
  const int wid = tid >> 6;
  const int wr = wid >> 2, wc = wid & 3;    // wave grid 2(M) x 4(N)
  const int lrow = lane & 15, g = lane >> 4, x7 = lrow & 7;
  const int ck0 = (g ^ x7) * 8;
  const int ck1 = ((4 + g) ^ x7) * 8;
  const int aoff = (wr * 64 + lrow) * 64;
  const int boff = (wc * 32 + lrow) * 64;

  f32x4 acc[8][4] = {};
  bf16x8 af[4][2], bf[2][2][2];

  const int NT = K >> 6;
  const int NITER = NT >> 1;

  // prologue: tile0 full + tile1 {A_first,B_first,B_second}; wait tile0 landed
  STG_A(0, 0, 0); STG_A(0, 1, 0); STG_B(0, 0, 0); STG_B(0, 1, 0);
  STG_A(1, 0, 1); STG_B(1, 0, 1); STG_B(1, 1, 1);
  VMW6();
  BAR(); SCB();

  for (int it = 0; it < NITER; ++it) {
    const int tb = 2 * it + 1;
    const int tn0 = 2 * it + 2;
    const int tn1 = 2 * it + 3;
    const bool more0 = tn0 < NT;
    const bool more1 = tn1 < NT;
    const bool last = (it + 1 == NITER);

    // ===== group 1: ph1, ph2 =====
    STG_A(1, 1, tb);             // buf1.A2 <- tile tb (read prev-ph7; B4 between)
    LDA(0, 0); LDB(0, 0);        // r1 (q1 operands)
    LDB(0, 1);                   // r2 (q2 operands) - overlaps q1 via compiler waits
    MM(0, 0);                    // q1
    MM(0, 1);                    // q2
    BAR(); SCB();                // B1

    // ===== group 2: ph3, ph4 =====
    if (more0) { STG_A(0, 0, tn0); STG_B(0, 0, tn0); }   // read@ph1 (B1 between)
    LDA(0, 1);                   // r3 (q3/q4 A operands)
    MM(1, 0);                    // q3 (bf[0] still live from r1)
    if (more0) STG_B(0, 1, tn0);                          // read@ph2 (B1)
    MM(1, 1);                    // q4 (bf[1] live from r2)
    if (last) { VMW0(); } else { VMW6(); }   // RAW gate for buf1 reads
    BAR(); SCB();                // B2

    // ===== group 3: ph5, ph6 =====
    if (more0) STG_A(0, 1, tn0);                          // read@ph3 (B2)
    LDA(1, 0); LDB(1, 0);        // r5
    LDB(1, 1);                   // r6
    MM(0, 0);                    // q5
    MM(0, 1);                    // q6
    BAR(); SCB();                // B3

    // ===== group 4: ph7, ph8 =====
    if (more1) { STG_A(1, 0, tn1); STG_B(1, 0, tn1); }    // read@ph5 (B3)
    LDA(1, 1);                   // r7
    MM(1, 0);                    // q7
    if (more1) STG_B(1, 1, tn1);                          // read@ph6 (B3)
    MM(1, 1);                    // q8
    if (more1) VMW6();           // RAW gate for next-iter buf0 reads
    BAR(); SCB();                // B4
  }

  // epilogue: m-outer, i-mid, n-inner so the 4 stores covering one output
  // 128B line (cols colb..colb+63 of a row) issue back-to-back.
  const int colb = cb * 256 + wc * 64;
  const int rowb = row0 + wr * 128;
  float bv[4];
#pragma unroll
  for (int n = 0; n < 4; ++n)
    bv[n] = bias[(size_t)e * N + colb + n * 16 + lrow];
#pragma unroll
  for (int m = 0; m < 8; ++m) {
    const int mq = m >> 2, mm = m & 3;
    const int gr = rowb + mq * 64 + mm * 16 + g * 4;
#pragma unroll
    for (int i = 0; i < 4; ++i) {
      const int grow = gr + i;
      float sw = (EPI == 1) ? slot_w[grow] : 0.f;
      ushort* crow = Cout + (size_t)grow * N + colb + lrow;
#pragma unroll
      for (int n = 0; n < 4; ++n) {
        float v = acc[m][n][i] + bv[n];
        if (EPI == 0) v = gelu_f(v);
        else          v *= sw;
        crow[n * 16] = f2bf(v);
      }
    }
  }
}

// out = x + Y[slot0] + Y[slot1]
__global__ __launch_bounds__(256) void combine_kernel(
    const float* __restrict__ x, const ushort* __restrict__ Yp,
    const int* __restrict__ token_slot, float* __restrict__ out)
{
  int t = blockIdx.x;
  int s0 = token_slot[2 * t], s1 = token_slot[2 * t + 1];
  int c = threadIdx.x * 8;
  const float* xr = x + (size_t)t * HID + c;
  u16x8 y0 = *(const u16x8*)&Yp[(size_t)s0 * HID + c];
  u16x8 y1 = *(const u16x8*)&Yp[(size_t)s1 * HID + c];
  float4 xa = *(const float4*)xr;
  float4 xb = *(const float4*)(xr + 4);
  float4 oa, ob;
  oa.x = xa.x + bf2f(y0[0]) + bf2f(y1[0]);
  oa.y = xa.y + bf2f(y0[1]) + bf2f(y1[1]);
  oa.z = xa.z + bf2f(y0[2]) + bf2f(y1[2]);
  oa.w = xa.w + bf2f(y0[3]) + bf2f(y1[3]);
  ob.x = xb.x + bf2f(y0[4]) + bf2f(y1[4]);
  ob.y = xb.y + bf2f(y0[5]) + bf2f(y1[5]);
  ob.z = xb.z + bf2f(y0[6]) + bf2f(y1[6]);
  ob.w = xb.w + bf2f(y0[7]) + bf2f(y1[7]);
  float* orow = out + (size_t)t * HID + c;
  *(float4*)orow = oa;
  *(float4*)(orow + 4) = ob;
}

extern "C" void kernel_launch(void* const* d_in, const int* in_sizes, int n_in,
                              void* d_out, int out_size, void* d_ws, size_t ws_size,
                              hipStream_t stream)
{
  const float* x  = (const float*)d_in[0];
  const float* gw = (const float*)d_in[1];
  const float* w1 = (const float*)d_in[2];
  const float* b1 = (const float*)d_in[3];
  const float* w2 = (const float*)d_in[4];
  const float* b2 = (const float*)d_in[5];
  float* out = (float*)d_out;

  char* ws = (char*)d_ws;
  // wT holds w1t during gemm1, then w2t for gemm2.
  ushort* wT  = (ushort*)(ws + 0);            // [E][out][K] bf16: 268,435,456
  ushort* Hb  = (ushort*)(ws + 268435456);    // [MAXR][FFN] bf16: 301,989,888
  ushort* Xg  = (ushort*)(ws + 570425344);    // [MAXR][HID] bf16: 75,497,472
  ushort* Yp  = Xg;                           // Ypair overlays Xg
  char* sm = ws + 645922816;
  int*   slot_token = (int*)(sm);
  float* slot_w     = (float*)(sm + 73728);
  int*   token_slot = (int*)(sm + 147456);
  int*   topk_idx   = (int*)(sm + 212992);
  float* topk_w     = (float*)(sm + 278528);
  int*   counts     = (int*)(sm + 344064);
  int*   cursors    = (int*)(sm + 344096);
  int*   offs       = (int*)(sm + 344128);

  hipMemsetAsync(counts, 0, 64, stream);
  hipMemsetAsync(slot_token, 0xFF, MAXR * 4, stream);

  router_kernel<<<dim3(T_TOK / 4), dim3(256), 0, stream>>>(x, gw, topk_idx, topk_w, counts);
  offsets_kernel<<<dim3(1), dim3(64), 0, stream>>>(counts, offs);
  scatter_kernel<<<dim3(T_TOK / 256), dim3(256), 0, stream>>>(
      topk_idx, topk_w, offs, cursors, slot_token, slot_w, token_slot);
  gather_kernel<<<dim3(MAXR), dim3(256), 0, stream>>>(x, slot_token, Xg);

  // w1 fp32 [H][F] -> bf16 [F][H] per expert
  transpose_convert_kernel<<<dim3(FFN_ / 64, HID / 64, NE), dim3(256), 0, stream>>>(
      w1, wT, HID, FFN_);
  gemm256_kernel<0><<<dim3((FFN_ / 256) * (MAXR / 256)), dim3(512), 0, stream>>>(
      Xg, wT, b1, Hb, nullptr, offs, HID, FFN_, MAXR / 256);

  // w2 fp32 [F][H] -> bf16 [H][F] per expert (reuses wT)
  transpose_convert_kernel<<<dim3(HID / 64, FFN_ / 64, NE), dim3(256), 0, stream>>>(
      w2, wT, FFN_, HID);
  gemm256_kernel<1><<<dim3((HID / 256) * (MAXR / 256)), dim3(512), 0, stream>>>(
      Hb, wT, b2, Yp, slot_w, offs, FFN_, HID, MAXR / 256);

  combine_kernel<<<dim3(T_TOK), dim3(256), 0, stream>>>(x, Yp, token_slot, out);
}